// Round 6
// baseline (7065.343 us; speedup 1.0000x reference)
//
#include <hip/hip_runtime.h>
#include <cstdint>
#include <cmath>

typedef unsigned short u16;
typedef unsigned long long u64;
typedef __bf16 v8bf __attribute__((ext_vector_type(8)));
typedef float v4f __attribute__((ext_vector_type(4)));

__device__ __forceinline__ u16 f2bf(float f) {
    unsigned int u = __float_as_uint(f);
    u += 0x7fffu + ((u >> 16) & 1u);   // round-to-nearest-even
    return (u16)(u >> 16);
}
__device__ __forceinline__ float sigmoidf_(float x) { return 1.0f / (1.0f + __expf(-x)); }
__device__ __forceinline__ float tanhf_(float x) {
    float e = __expf(2.0f * x);
    return 1.0f - 2.0f / (e + 1.0f);
}

// aux (cpol): SC0=1, NT=2, SC1=16. 17 = SC0|SC1 (MALL-coherent, no L2 alloc),
// 2 = NT (stream, evict-first: don't thrash L2), 0 = normal cached (weights).
#define AGLD(g, l, aux)                                                    \
    __builtin_amdgcn_global_load_lds(                                      \
        (const __attribute__((address_space(1))) unsigned int*)(g),        \
        (__attribute__((address_space(3))) unsigned int*)(l), 16, 0, aux)

__device__ __forceinline__ u64 aload64(const u16* p) {
    return __hip_atomic_load((const u64*)p, __ATOMIC_RELAXED, __HIP_MEMORY_SCOPE_AGENT);
}
__device__ __forceinline__ void astore64(u16* p, u64 v) {
    __hip_atomic_store((u64*)p, v, __ATOMIC_RELAXED, __HIP_MEMORY_SCOPE_AGENT);
}

// ---------------------------------------------------------------------------
// Flush-free grid barrier: monotonic 2-level counter tree, ALL RELAXED atomics
// (no acquire/release -> no buffer_inv / buffer_wbl2 -> L2 weight residency
// survives). Ordering = vmcnt(0) drain + control dependency + s_barrier.
// ---------------------------------------------------------------------------
__device__ __forceinline__ void grid_bar(unsigned* bar, int phase) {
    asm volatile("s_waitcnt vmcnt(0)" ::: "memory");   // sc1 stores reached MALL
    __syncthreads();
    if (threadIdx.x == 0) {
        unsigned* leaf = bar + 32 * ((blockIdx.x & 7) + 1);
        unsigned v = __hip_atomic_fetch_add(leaf, 1u, __ATOMIC_RELAXED, __HIP_MEMORY_SCOPE_AGENT);
        if ((v & 31u) == 31u)   // last of this leaf's 32 blocks for this phase
            __hip_atomic_fetch_add(bar, 1u, __ATOMIC_RELAXED, __HIP_MEMORY_SCOPE_AGENT);
        const unsigned target = 8u * (unsigned)phase;  // root grows by 8/phase
        while (__hip_atomic_load(bar, __ATOMIC_RELAXED, __HIP_MEMORY_SCOPE_AGENT) < target)
            __builtin_amdgcn_s_sleep(4);
    }
    __syncthreads();
}

// ---------------------------------------------------------------------------
// One LSTM-layer block tile: gates = [A1|A2] @ W^T + bias, fused cell update.
// BM=128 x BN=128, BK=64, 4 waves (2x2) of 64x64; double-buffered
// global_load_lds staging, 16B-chunk XOR swizzle (2-way = free aliasing).
// Cell state lives in REGISTERS (cst[16]/thread, same (b,U) every phase) --
// zero memory traffic, zero L2 allocation. Weights aux=0 stay L2-resident.
// ---------------------------------------------------------------------------
__device__ __forceinline__ void gemm_layer(
    const u16* __restrict__ A1, int K1, int S1, int a1aux,
    const u16* __restrict__ A2, int S2,
    const u16* __restrict__ W, int Ktot,
    const float* __restrict__ bias,
    float* __restrict__ cst,            // [16] thread-private cell state
    u16* __restrict__ Hout,
    int m0, int n0, u16* smem)
{
    const int tid  = threadIdx.x;
    const int wave = tid >> 6;
    const int lane = tid & 63;
    const int l16  = lane & 15;
    const int lq   = lane >> 4;
    const int wrb  = (wave >> 1) * 64;
    const int wcb  = (wave & 1) * 64;

    v4f acc[4][4];
#pragma unroll
    for (int i = 0; i < 4; ++i)
#pragma unroll
        for (int j = 0; j < 4; ++j) acc[i][j] = (v4f){0.f, 0.f, 0.f, 0.f};

    const int srow = tid >> 3;
    const int skc  = tid & 7;

    auto stage_tile = [&](int k0, int buf) {
        u16* At = smem + buf * 16384;     // [128][8 chunks of 16B]
        u16* Bt = At + 8192;
        const u16* src; int kof, st, aux;
        if (k0 < K1) { src = A1; kof = k0;      st = S1; aux = a1aux; }
        else         { src = A2; kof = k0 - K1; st = S2; aux = 17; }
        if (aux == 17) {
#pragma unroll
            for (int r = 0; r < 4; ++r) {
                int c = tid + r * 256;
                int row = srow + r * 32;
                int kc  = skc ^ (row & 7);
                AGLD(src + (size_t)(m0 + row) * st + kof + kc * 8, At + c * 8, 17);
            }
        } else if (aux == 2) {
#pragma unroll
            for (int r = 0; r < 4; ++r) {
                int c = tid + r * 256;
                int row = srow + r * 32;
                int kc  = skc ^ (row & 7);
                AGLD(src + (size_t)(m0 + row) * st + kof + kc * 8, At + c * 8, 2);
            }
        }
#pragma unroll
        for (int r = 0; r < 4; ++r) {
            int c = tid + r * 256;
            int row = srow + r * 32;
            int kc  = skc ^ (row & 7);
            AGLD(W + (size_t)(n0 + row) * Ktot + k0 + kc * 8, Bt + c * 8, 0);
        }
    };

    const int nt = Ktot >> 6;
    stage_tile(0, 0);
    for (int it = 0; it < nt; ++it) {
        __syncthreads();                       // tile `it` landed (all waves)
        if (it + 1 < nt) stage_tile((it + 1) << 6, (it + 1) & 1);
        const u16* At = smem + (it & 1) * 16384;
        const u16* Bt = At + 8192;
#pragma unroll
        for (int kk = 0; kk < 64; kk += 32) {
            const int kcb = kk >> 3;
            v8bf a[4], b[4];
#pragma unroll
            for (int mi = 0; mi < 4; ++mi) {
                int row = wrb + mi * 16 + l16;
                int p = row * 8 + ((kcb + lq) ^ (row & 7));
                a[mi] = *(const v8bf*)(At + p * 8);
            }
#pragma unroll
            for (int ni = 0; ni < 4; ++ni) {
                int row = wcb + ni * 16 + l16;
                int p = row * 8 + ((kcb + lq) ^ (row & 7));
                b[ni] = *(const v8bf*)(Bt + p * 8);
            }
#pragma unroll
            for (int mi = 0; mi < 4; ++mi)
#pragma unroll
                for (int ni = 0; ni < 4; ++ni)
                    acc[mi][ni] = __builtin_amdgcn_mfma_f32_16x16x32_bf16(
                        a[mi], b[ni], acc[mi][ni], 0, 0, 0);
        }
    }
    __syncthreads();

    // epilogue in two row-halves (gates buffer 64x132 f32 = 33.8 KB in smem)
    float* gates = (float*)smem;
#pragma unroll
    for (int p = 0; p < 2; ++p) {
        if ((wave >> 1) == p) {
#pragma unroll
            for (int mi = 0; mi < 4; ++mi)
#pragma unroll
                for (int ni = 0; ni < 4; ++ni) {
                    int col = wcb + ni * 16 + l16;
                    float bs = bias[n0 + col];
#pragma unroll
                    for (int r = 0; r < 4; ++r) {
                        int row = mi * 16 + lq * 4 + r;
                        gates[row * 132 + col] = acc[mi][ni][r] + bs;
                    }
                }
        }
        __syncthreads();
#pragma unroll
        for (int j = 0; j < 2; ++j) {
            int it2 = tid + j * 256;          // 512 items = 64 rows x 8 unit-quads
            int row = it2 >> 3, ug = (it2 & 7) * 4;
            const float* gp = gates + row * 132 + ug * 4;   // 16 consecutive f32
            int b = m0 + p * 64 + row;
            int U = (n0 >> 2) + ug;
            float* cs = cst + (p * 2 + j) * 4;
            u64 hq; u16* hqs = (u16*)&hq;
#pragma unroll
            for (int q = 0; q < 4; ++q) {
                float gi = gp[q * 4 + 0], gf = gp[q * 4 + 1];
                float gg = gp[q * 4 + 2], go = gp[q * 4 + 3];
                float i_ = sigmoidf_(gi);
                float f_ = sigmoidf_(gf);
                float g_ = tanhf_(gg);
                float o_ = sigmoidf_(go);
                float c2 = f_ * cs[q] + i_ * g_;
                cs[q] = c2;
                hqs[q] = f2bf(o_ * tanhf_(c2));
            }
            astore64(Hout + (size_t)b * 1024 + U, hq);
        }
        __syncthreads();
    }
}

// ---------------------------------------------------------------------------
// Decoder head (blocks 0..15): delta = h1 @ fc_w^T + fc_b ; LN + residual.
// ---------------------------------------------------------------------------
__device__ __forceinline__ void fc_ln(
    int blk, const u16* __restrict__ H1, const u16* __restrict__ Wf,
    const float* __restrict__ fcb, const float* __restrict__ alpha,
    const float* __restrict__ beta,
    const float* __restrict__ decprev, float* __restrict__ outp,
    u16* __restrict__ decnext)
{
    const int tid  = threadIdx.x;
    const int wave = tid >> 6, lane = tid & 63;
    const int l16  = lane & 15, lq = lane >> 4;
    const int b0   = blk * 64 + wave * 16;

    v4f acc[5];
#pragma unroll
    for (int i = 0; i < 5; ++i) acc[i] = (v4f){0.f, 0.f, 0.f, 0.f};

    for (int k = 0; k < 1024; k += 32) {
        const u16* ap = H1 + (size_t)(b0 + l16) * 1024 + k + lq * 8;
        union { u64 q[2]; v8bf v; } uu;
        uu.q[0] = aload64(ap);
        uu.q[1] = aload64(ap + 4);
        v8bf a = uu.v;
#pragma unroll
        for (int ni = 0; ni < 5; ++ni) {
            v8bf bb = *(const v8bf*)(Wf + (size_t)(ni * 16 + l16) * 1024 + k + lq * 8);
            acc[ni] = __builtin_amdgcn_mfma_f32_16x16x32_bf16(a, bb, acc[ni], 0, 0, 0);
        }
    }

    float av[5], bv[5], fb[5]; int valid[5];
#pragma unroll
    for (int ni = 0; ni < 5; ++ni) {
        int col = ni * 16 + l16;
        valid[ni] = col < 66;
        fb[ni] = valid[ni] ? fcb[col]   : 0.f;
        av[ni] = valid[ni] ? alpha[col] : 0.f;
        bv[ni] = valid[ni] ? beta[col]  : 0.f;
    }
#pragma unroll
    for (int r = 0; r < 4; ++r) {
        int b = b0 + lq * 4 + r;
        float d[5];
        float s = 0.f;
#pragma unroll
        for (int ni = 0; ni < 5; ++ni) {
            d[ni] = valid[ni] ? (acc[ni][r] + fb[ni]) : 0.f;
            s += d[ni];
        }
#pragma unroll
        for (int m = 1; m < 16; m <<= 1) s += __shfl_xor(s, m, 64);
        float mean = s * (1.f / 66.f);
        float vs = 0.f;
#pragma unroll
        for (int ni = 0; ni < 5; ++ni) {
            float t = valid[ni] ? (d[ni] - mean) : 0.f;
            vs += t * t;
        }
#pragma unroll
        for (int m = 1; m < 16; m <<= 1) vs += __shfl_xor(vs, m, 64);
        float inv = rsqrtf(vs * (1.f / 66.f) + 1e-5f);
#pragma unroll
        for (int ni = 0; ni < 5; ++ni) {
            if (valid[ni]) {
                int col = ni * 16 + l16;
                float y = (d[ni] - mean) * inv * av[ni] + bv[ni]
                        + decprev[(size_t)b * 3300 + col];
                outp[(size_t)b * 3300 + col] = y;
                __hip_atomic_store(decnext + (size_t)b * 128 + col, f2bf(y),
                                   __ATOMIC_RELAXED, __HIP_MEMORY_SCOPE_AGENT);
            }
        }
    }
}

// ---------------------------------------------------------------------------
// Persistent kernel: all 99 steps, flush-free grid barriers between phases.
// Encoder pipelined: [GEMM1(s); GEMM0(s+1)] per barrier interval.
// ---------------------------------------------------------------------------
__global__ __launch_bounds__(256)
void lstm_persistent(const u16* __restrict__ Xbuf, u16* __restrict__ DEC,
                     u16* __restrict__ H0, u16* __restrict__ H1,
                     const u16* __restrict__ Wc0, const u16* __restrict__ Wc1,
                     const float* __restrict__ B0p, const float* __restrict__ B1p,
                     const u16* __restrict__ fcwb, const float* __restrict__ fcb,
                     const float* __restrict__ alpha, const float* __restrict__ beta,
                     const float* __restrict__ x, float* __restrict__ out,
                     unsigned* __restrict__ bar)
{
    __shared__ alignas(16) u16 smem[32768];   // 64 KB
    const int blk = blockIdx.x;
    const int m0  = (blk >> 5) * 128;
    const int n0  = (blk & 31) * 128;   // n%8 == blk%8 -> W slice pinned per XCD
    const size_t HSZ = 1024 * 1024;
    int ph = 0;

    float c0s[16], c1s[16];             // register-resident cell state
#pragma unroll
    for (int i = 0; i < 16; ++i) { c0s[i] = 0.f; c1s[i] = 0.f; }

    // ---- encoder: gemm0(0), then [gemm1(s); gemm0(s+1)] phases
    gemm_layer(Xbuf, 128, 128, 2, H0, 1024, Wc0, 1152, B0p, c0s, H0 + HSZ, m0, n0, smem);
    grid_bar(bar, ++ph);
    for (int s = 0; s < 48; ++s) {
        const u16* h0w = H0 + (size_t)((s + 1) & 1) * HSZ;
        gemm_layer(h0w, 1024, 1024, 17, H1 + (size_t)(s & 1) * HSZ, 1024,
                   Wc1, 2048, B1p, c1s, H1 + (size_t)((s + 1) & 1) * HSZ, m0, n0, smem);
        gemm_layer(Xbuf + (size_t)(s + 1) * (1024 * 128), 128, 128, 2, h0w, 1024,
                   Wc0, 1152, B0p, c0s, H0 + (size_t)(s & 1) * HSZ, m0, n0, smem);
        grid_bar(bar, ++ph);
    }
    gemm_layer(H0 + HSZ, 1024, 1024, 17, H1, 1024,
               Wc1, 2048, B1p, c1s, H1 + HSZ, m0, n0, smem);   // step 48
    grid_bar(bar, ++ph);

    // ---- decoder: 3 phases/step
    for (int s = 49; s < 99; ++s) {
        int d = s - 49;
        const u16* A1 = DEC + (size_t)(d & 1) * (1024 * 128);
        u16* h0r = H0 + (size_t)(s & 1) * HSZ;
        u16* h0w = H0 + (size_t)((s + 1) & 1) * HSZ;
        u16* h1r = H1 + (size_t)(s & 1) * HSZ;
        u16* h1w = H1 + (size_t)((s + 1) & 1) * HSZ;

        gemm_layer(A1, 128, 128, 17, h0r, 1024, Wc0, 1152, B0p, c0s, h0w, m0, n0, smem);
        grid_bar(bar, ++ph);
        gemm_layer(h0w, 1024, 1024, 17, h1r, 1024, Wc1, 2048, B1p, c1s, h1w, m0, n0, smem);
        grid_bar(bar, ++ph);
        if (blk < 16) {
            const float* decprev = (d == 0) ? (x + 49 * 66) : (out + (size_t)(d - 1) * 66);
            fc_ln(blk, h1w, fcwb, fcb, alpha, beta, decprev, out + (size_t)d * 66,
                  DEC + (size_t)((d + 1) & 1) * (1024 * 128));
        }
        grid_bar(bar, ++ph);
    }
}

// ---------------------------------------------------------------------------
// init kernels: weight reorder/convert (gate-interleaved rows), x->bf16, zeros
// ---------------------------------------------------------------------------
__global__ void k_init_w0(const float* __restrict__ Wih, const float* __restrict__ Whh,
                          u16* __restrict__ Wc)
{
    int idx = blockIdx.x * 256 + threadIdx.x;
    if (idx >= 4096 * 1152) return;
    int jp = idx / 1152, k = idx - jp * 1152;
    int u = jp >> 2, g = jp & 3;           // j' = u*4+g  <-  j = g*1024+u
    float v = 0.f;
    if (k < 66)        v = Wih[(g * 1024 + u) * 66 + k];
    else if (k >= 128) v = Whh[(size_t)(g * 1024 + u) * 1024 + (k - 128)];
    Wc[idx] = f2bf(v);
}
__global__ void k_init_w1(const float* __restrict__ Wih, const float* __restrict__ Whh,
                          u16* __restrict__ Wc)
{
    int idx = blockIdx.x * 256 + threadIdx.x;   // 4096*2048
    int jp = idx >> 11, k = idx & 2047;
    int u = jp >> 2, g = jp & 3;
    float v = (k < 1024) ? Wih[(size_t)(g * 1024 + u) * 1024 + k]
                         : Whh[(size_t)(g * 1024 + u) * 1024 + (k - 1024)];
    Wc[idx] = f2bf(v);
}
__global__ void k_init_fcw(const float* __restrict__ fcw, u16* __restrict__ Wb)
{
    int idx = blockIdx.x * 256 + threadIdx.x;   // 80*1024
    int r = idx >> 10, k = idx & 1023;
    float v = (r < 66) ? fcw[(size_t)r * 1024 + k] : 0.f;
    Wb[idx] = f2bf(v);
}
__global__ void k_init_bias(const float* __restrict__ b0, const float* __restrict__ b1,
                            float* __restrict__ B0p, float* __restrict__ B1p)
{
    int idx = blockIdx.x * 256 + threadIdx.x;   // 8192
    if (idx < 4096) B0p[idx] = b0[(idx & 3) * 1024 + (idx >> 2)];
    else { int j = idx - 4096; B1p[j] = b1[(j & 3) * 1024 + (j >> 2)]; }
}
__global__ void k_init_x(const float* __restrict__ x, u16* __restrict__ Xbuf,
                         u16* __restrict__ DEC0)
{
    int idx = blockIdx.x * 256 + threadIdx.x;   // 50*1024*128
    int t = idx >> 17;
    int b = (idx >> 7) & 1023;
    int c = idx & 127;
    float v = (c < 66) ? x[(size_t)b * 3300 + t * 66 + c] : 0.f;
    u16 h = f2bf(v);
    if (t < 49) Xbuf[idx] = h;
    else        DEC0[b * 128 + c] = h;
}
__global__ void k_init_state(u16* __restrict__ H0z, u16* __restrict__ H1z,
                             u16* __restrict__ DEC1, unsigned* __restrict__ bar)
{
    int idx = blockIdx.x * 256 + threadIdx.x;   // 1024*1024
    H0z[idx] = 0; H1z[idx] = 0;
    if (idx < 1024 * 128) DEC1[idx] = 0;
    if (idx < 1024) bar[idx] = 0u;
}

// ---------------------------------------------------------------------------
extern "C" void kernel_launch(void* const* d_in, const int* in_sizes, int n_in,
                              void* d_out, int out_size, void* d_ws, size_t ws_size,
                              hipStream_t stream)
{
    const float* x     = (const float*)d_in[0];
    const float* Wih0  = (const float*)d_in[1];
    const float* Whh0  = (const float*)d_in[2];
    const float* b0    = (const float*)d_in[3];
    const float* Wih1  = (const float*)d_in[4];
    const float* Whh1  = (const float*)d_in[5];
    const float* b1    = (const float*)d_in[6];
    const float* fcw   = (const float*)d_in[7];
    const float* fcb   = (const float*)d_in[8];
    const float* alpha = (const float*)d_in[9];
    const float* beta  = (const float*)d_in[10];
    float* out = (float*)d_out;

    char* p = (char*)d_ws;
    auto take = [&](size_t bytes) { char* r = p; p += (bytes + 255) & ~(size_t)255; return r; };
    u16*      Wc0  = (u16*)take((size_t)4096 * 1152 * 2);
    u16*      Wc1  = (u16*)take((size_t)4096 * 2048 * 2);
    u16*      fcwb = (u16*)take((size_t)80 * 1024 * 2);
    float*    B0p  = (float*)take(4096 * 4);
    float*    B1p  = (float*)take(4096 * 4);
    u16*      Xbuf = (u16*)take((size_t)49 * 1024 * 128 * 2);
    u16*      DEC  = (u16*)take((size_t)2 * 1024 * 128 * 2);
    u16*      H0   = (u16*)take((size_t)2 * 1024 * 1024 * 2);
    u16*      H1   = (u16*)take((size_t)2 * 1024 * 1024 * 2);
    unsigned* bar  = (unsigned*)take(4096);

    k_init_w0<<<18432, 256, 0, stream>>>(Wih0, Whh0, Wc0);
    k_init_w1<<<32768, 256, 0, stream>>>(Wih1, Whh1, Wc1);
    k_init_fcw<<<320, 256, 0, stream>>>(fcw, fcwb);
    k_init_bias<<<32, 256, 0, stream>>>(b0, b1, B0p, B1p);
    k_init_x<<<25600, 256, 0, stream>>>(x, Xbuf, DEC);
    k_init_state<<<4096, 256, 0, stream>>>(H0, H1, DEC + 1024 * 128, bar);

    lstm_persistent<<<dim3(256), 256, 0, stream>>>(
        Xbuf, DEC, H0, H1, Wc0, Wc1, B0p, B1p,
        fcwb, fcb, alpha, beta, x, out, bar);
}

// Round 7
// 6174.878 us; speedup vs baseline: 1.1442x; 1.1442x over previous
//
#include <hip/hip_runtime.h>
#include <cstdint>
#include <cmath>

typedef unsigned short u16;
typedef unsigned long long u64;
typedef __bf16 v8bf __attribute__((ext_vector_type(8)));
typedef float v4f __attribute__((ext_vector_type(4)));

__device__ __forceinline__ u16 f2bf(float f) {
    unsigned int u = __float_as_uint(f);
    u += 0x7fffu + ((u >> 16) & 1u);   // round-to-nearest-even
    return (u16)(u >> 16);
}
__device__ __forceinline__ float sigmoidf_(float x) { return 1.0f / (1.0f + __expf(-x)); }
__device__ __forceinline__ float tanhf_(float x) {
    float e = __expf(2.0f * x);
    return 1.0f - 2.0f / (e + 1.0f);
}

// aux (cpol): SC0=1, NT=2, SC1=16. 17 = SC0|SC1 (MALL-coherent, no L2 alloc),
// 2 = NT (stream), 0 = normal cached (weights stay L2-resident).
#define AGLD(g, l, aux)                                                    \
    __builtin_amdgcn_global_load_lds(                                      \
        (const __attribute__((address_space(1))) unsigned int*)(g),        \
        (__attribute__((address_space(3))) unsigned int*)(l), 16, 0, aux)

__device__ __forceinline__ void astore64(u16* p, u64 v) {
    __hip_atomic_store((u64*)p, v, __ATOMIC_RELAXED, __HIP_MEMORY_SCOPE_AGENT);
}
__device__ __forceinline__ void astore16(u16* p, u16 v) {
    __hip_atomic_store(p, v, __ATOMIC_RELAXED, __HIP_MEMORY_SCOPE_AGENT);
}

// ---------------------------------------------------------------------------
// Flush-free grid barrier: monotonic 2-level counter tree, ALL RELAXED atomics
// (no acquire/release -> no buffer_inv/wbl2 -> L2 weight residency survives).
// Ordering = vmcnt(0) drain + control dependency + s_barrier.
// ---------------------------------------------------------------------------
__device__ __forceinline__ void grid_bar(unsigned* bar, int phase) {
    asm volatile("s_waitcnt vmcnt(0)" ::: "memory");
    __syncthreads();
    if (threadIdx.x == 0) {
        unsigned* leaf = bar + 32 * ((blockIdx.x & 7) + 1);
        unsigned v = __hip_atomic_fetch_add(leaf, 1u, __ATOMIC_RELAXED, __HIP_MEMORY_SCOPE_AGENT);
        if ((v & 31u) == 31u)
            __hip_atomic_fetch_add(bar, 1u, __ATOMIC_RELAXED, __HIP_MEMORY_SCOPE_AGENT);
        const unsigned target = 8u * (unsigned)phase;
        while (__hip_atomic_load(bar, __ATOMIC_RELAXED, __HIP_MEMORY_SCOPE_AGENT) < target)
            __builtin_amdgcn_s_sleep(2);
    }
    __syncthreads();
}

// ---------------------------------------------------------------------------
// GEMM tile engine: accumulate K64-tiles [t0, t1) of gates = [A1|A2] @ W^T.
// BM=128 x BN=128, 4 waves (2x2) of 64x64; double-buffered global_load_lds
// staging with 16B-chunk XOR swizzle. acc persists in caller (can span
// grid barriers for split-phase GEMMs).
// ---------------------------------------------------------------------------
__device__ __forceinline__ void gemm_tiles(
    v4f (&acc)[4][4],
    const u16* __restrict__ A1, int K1, int S1, int a1aux,
    const u16* __restrict__ A2, int S2,
    const u16* __restrict__ W, int Ktot,
    int m0, int n0, u16* smem, int t0, int t1)
{
    const int tid  = threadIdx.x;
    const int wave = tid >> 6;
    const int lane = tid & 63;
    const int l16  = lane & 15;
    const int lq   = lane >> 4;
    const int wrb  = (wave >> 1) * 64;
    const int wcb  = (wave & 1) * 64;
    const int srow = tid >> 3;
    const int skc  = tid & 7;

    auto stage_tile = [&](int t, int buf) {
        int k0 = t << 6;
        u16* At = smem + buf * 16384;     // [128][8 chunks of 16B]
        u16* Bt = At + 8192;
        const u16* src; int kof, st, aux;
        if (k0 < K1) { src = A1; kof = k0;      st = S1; aux = a1aux; }
        else         { src = A2; kof = k0 - K1; st = S2; aux = 17; }
        if (aux == 17) {
#pragma unroll
            for (int r = 0; r < 4; ++r) {
                int c = tid + r * 256;
                int row = srow + r * 32;
                int kc  = skc ^ (row & 7);
                AGLD(src + (size_t)(m0 + row) * st + kof + kc * 8, At + c * 8, 17);
            }
        } else {
#pragma unroll
            for (int r = 0; r < 4; ++r) {
                int c = tid + r * 256;
                int row = srow + r * 32;
                int kc  = skc ^ (row & 7);
                AGLD(src + (size_t)(m0 + row) * st + kof + kc * 8, At + c * 8, 2);
            }
        }
#pragma unroll
        for (int r = 0; r < 4; ++r) {
            int c = tid + r * 256;
            int row = srow + r * 32;
            int kc  = skc ^ (row & 7);
            AGLD(W + (size_t)(n0 + row) * Ktot + (t << 6) + kc * 8, Bt + c * 8, 0);
        }
    };

    stage_tile(t0, 0);
    for (int t = t0; t < t1; ++t) {
        __syncthreads();
        if (t + 1 < t1) stage_tile(t + 1, (t + 1 - t0) & 1);
        const u16* At = smem + ((t - t0) & 1) * 16384;
        const u16* Bt = At + 8192;
#pragma unroll
        for (int kk = 0; kk < 64; kk += 32) {
            const int kcb = kk >> 3;
            v8bf a[4], b[4];
#pragma unroll
            for (int mi = 0; mi < 4; ++mi) {
                int row = wrb + mi * 16 + l16;
                int p = row * 8 + ((kcb + lq) ^ (row & 7));
                a[mi] = *(const v8bf*)(At + p * 8);
            }
#pragma unroll
            for (int ni = 0; ni < 4; ++ni) {
                int row = wcb + ni * 16 + l16;
                int p = row * 8 + ((kcb + lq) ^ (row & 7));
                b[ni] = *(const v8bf*)(Bt + p * 8);
            }
#pragma unroll
            for (int mi = 0; mi < 4; ++mi)
#pragma unroll
                for (int ni = 0; ni < 4; ++ni)
                    acc[mi][ni] = __builtin_amdgcn_mfma_f32_16x16x32_bf16(
                        a[mi], b[ni], acc[mi][ni], 0, 0, 0);
        }
    }
    __syncthreads();
}

// ---------------------------------------------------------------------------
// LSTM epilogue: gates -> LDS (+bias), fused cell update; cst in registers.
// ---------------------------------------------------------------------------
__device__ __forceinline__ void gemm_epilogue(
    v4f (&acc)[4][4], const float* __restrict__ bias,
    float* __restrict__ cst, u16* __restrict__ Hout,
    int m0, int n0, u16* smem)
{
    const int tid  = threadIdx.x;
    const int wave = tid >> 6;
    const int lane = tid & 63;
    const int l16  = lane & 15;
    const int lq   = lane >> 4;
    const int wcb  = (wave & 1) * 64;
    float* gates = (float*)smem;   // 64x132 f32 = 33.8 KB
#pragma unroll
    for (int p = 0; p < 2; ++p) {
        if ((wave >> 1) == p) {
#pragma unroll
            for (int mi = 0; mi < 4; ++mi)
#pragma unroll
                for (int ni = 0; ni < 4; ++ni) {
                    int col = wcb + ni * 16 + l16;
                    float bs = bias[n0 + col];
#pragma unroll
                    for (int r = 0; r < 4; ++r) {
                        int row = mi * 16 + lq * 4 + r;
                        gates[row * 132 + col] = acc[mi][ni][r] + bs;
                    }
                }
        }
        __syncthreads();
#pragma unroll
        for (int j = 0; j < 2; ++j) {
            int it2 = tid + j * 256;
            int row = it2 >> 3, ug = (it2 & 7) * 4;
            const float* gp = gates + row * 132 + ug * 4;
            int b = m0 + p * 64 + row;
            int U = (n0 >> 2) + ug;
            float* cs = cst + (p * 2 + j) * 4;
            u64 hq; u16* hqs = (u16*)&hq;
#pragma unroll
            for (int q = 0; q < 4; ++q) {
                float gi = gp[q * 4 + 0], gf = gp[q * 4 + 1];
                float gg = gp[q * 4 + 2], go = gp[q * 4 + 3];
                float i_ = sigmoidf_(gi);
                float f_ = sigmoidf_(gf);
                float g_ = tanhf_(gg);
                float o_ = sigmoidf_(go);
                float c2 = f_ * cs[q] + i_ * g_;
                cs[q] = c2;
                hqs[q] = f2bf(o_ * tanhf_(c2));
            }
            astore64(Hout + (size_t)b * 1024 + U, hq);
        }
        __syncthreads();
    }
}

__device__ __forceinline__ void gemm_full(
    const u16* __restrict__ A1, int K1, int S1, int a1aux,
    const u16* __restrict__ A2, int S2,
    const u16* __restrict__ W, int Ktot, const float* __restrict__ bias,
    float* __restrict__ cst, u16* __restrict__ Hout,
    int m0, int n0, u16* smem)
{
    v4f acc[4][4];
#pragma unroll
    for (int i = 0; i < 4; ++i)
#pragma unroll
        for (int j = 0; j < 4; ++j) acc[i][j] = (v4f){0.f, 0.f, 0.f, 0.f};
    gemm_tiles(acc, A1, K1, S1, a1aux, A2, S2, W, Ktot, m0, n0, smem, 0, Ktot >> 6);
    gemm_epilogue(acc, bias, cst, Hout, m0, n0, smem);
}

// ---------------------------------------------------------------------------
// fc share (all 256 blocks; quad-group g=blk>>2 covers rows g*16..g*16+15,
// 4x redundant): delta = h1 @ fc_w^T + fc_b ; LN + residual; leader writes.
// H1 slice staged to LDS via sc0|sc1 DMA; K split over the 4 waves with an
// LDS partial-sum reduce. Wf is pre-swizzled fragment-contiguous.
// ---------------------------------------------------------------------------
__device__ __forceinline__ void fc_share(
    int blk, const u16* __restrict__ H1, const u16* __restrict__ Wf,
    const float* __restrict__ fcb, const float* __restrict__ alpha,
    const float* __restrict__ beta,
    const float* __restrict__ decprev, float* __restrict__ outp,
    u16* __restrict__ decnext, u16* smem)
{
    const int tid  = threadIdx.x;
    const int wave = tid >> 6, lane = tid & 63;
    const int l16  = lane & 15, lq = lane >> 4;
    const int g    = blk >> 2;
    const int b0   = g * 16;

    // stage 16 rows x 1024 cols bf16 = 2048 x 16B chunks (XOR-swizzled)
#pragma unroll
    for (int r = 0; r < 8; ++r) {
        int c = tid + r * 256;
        int row = c >> 7, ck = c & 127;
        AGLD(H1 + (size_t)(b0 + row) * 1024 + (ck ^ (row & 7)) * 8, smem + c * 8, 17);
    }
    __syncthreads();

    // each wave: 8 ksteps (K=256 slice)
    v4f pacc[5];
#pragma unroll
    for (int i = 0; i < 5; ++i) pacc[i] = (v4f){0.f, 0.f, 0.f, 0.f};
#pragma unroll
    for (int ks = 0; ks < 8; ++ks) {
        int kstep = wave * 8 + ks;
        int p = l16 * 128 + ((kstep * 4 + lq) ^ (l16 & 7));
        v8bf a = *(const v8bf*)(smem + p * 8);
#pragma unroll
        for (int ni = 0; ni < 5; ++ni) {
            const u16* wp = Wf + (size_t)(((kstep * 4 + lq) * 5 + ni) * 128) + l16 * 8;
            v8bf bb = *(const v8bf*)wp;
            pacc[ni] = __builtin_amdgcn_mfma_f32_16x16x32_bf16(a, bb, pacc[ni], 0, 0, 0);
        }
    }
    // partial exchange: part[wave][row16][col80] f32 at byte 32768
    float* part = (float*)(smem + 16384);
#pragma unroll
    for (int ni = 0; ni < 5; ++ni)
#pragma unroll
        for (int r = 0; r < 4; ++r)
            part[wave * 1280 + (lq * 4 + r) * 80 + ni * 16 + l16] = pacc[ni][r];
    __syncthreads();

    if (wave == 0) {
        float av[5], bv[5], fb[5]; int valid[5];
#pragma unroll
        for (int ni = 0; ni < 5; ++ni) {
            int col = ni * 16 + l16;
            valid[ni] = col < 66;
            fb[ni] = valid[ni] ? fcb[col]   : 0.f;
            av[ni] = valid[ni] ? alpha[col] : 0.f;
            bv[ni] = valid[ni] ? beta[col]  : 0.f;
        }
        const bool leader = (blk & 3) == 0;
#pragma unroll
        for (int r = 0; r < 4; ++r) {
            int row = lq * 4 + r;
            int b = b0 + row;
            float d[5];
            float s = 0.f;
#pragma unroll
            for (int ni = 0; ni < 5; ++ni) {
                float v = part[row * 80 + ni * 16 + l16]
                        + part[1280 + row * 80 + ni * 16 + l16]
                        + part[2560 + row * 80 + ni * 16 + l16]
                        + part[3840 + row * 80 + ni * 16 + l16];
                d[ni] = valid[ni] ? (v + fb[ni]) : 0.f;
                s += d[ni];
            }
#pragma unroll
            for (int m = 1; m < 16; m <<= 1) s += __shfl_xor(s, m, 64);
            float mean = s * (1.f / 66.f);
            float vs = 0.f;
#pragma unroll
            for (int ni = 0; ni < 5; ++ni) {
                float t = valid[ni] ? (d[ni] - mean) : 0.f;
                vs += t * t;
            }
#pragma unroll
            for (int m = 1; m < 16; m <<= 1) vs += __shfl_xor(vs, m, 64);
            float inv = rsqrtf(vs * (1.f / 66.f) + 1e-5f);
#pragma unroll
            for (int ni = 0; ni < 5; ++ni) {
                if (valid[ni] && leader) {
                    int col = ni * 16 + l16;
                    float y = (d[ni] - mean) * inv * av[ni] + bv[ni]
                            + decprev[(size_t)b * 3300 + col];
                    outp[(size_t)b * 3300 + col] = y;
                    astore16(decnext + (size_t)b * 128 + col, f2bf(y));
                }
            }
        }
    }
    __syncthreads();
}

// ---------------------------------------------------------------------------
// Persistent kernel: all 99 steps, flush-free grid barriers between phases.
// Encoder: [G1(s); G0(s+1)] per phase. Decoder per step: [G1(s)] |
// [fc(s) + G0(s+1) h0-part] | [G0(s+1) DEC-part + epilogue] — G0 acc spans
// the barrier in registers.
// ---------------------------------------------------------------------------
__global__ __launch_bounds__(256)
void lstm_persistent(const u16* __restrict__ Xbuf, u16* __restrict__ DEC,
                     u16* __restrict__ H0, u16* __restrict__ H1,
                     const u16* __restrict__ Wc0, const u16* __restrict__ Wc1,
                     const float* __restrict__ B0p, const float* __restrict__ B1p,
                     const u16* __restrict__ fcwb, const float* __restrict__ fcb,
                     const float* __restrict__ alpha, const float* __restrict__ beta,
                     const float* __restrict__ x, float* __restrict__ out,
                     unsigned* __restrict__ bar)
{
    __shared__ alignas(16) u16 smem[32768];   // 64 KB
    const int blk = blockIdx.x;
    const int m0  = (blk >> 5) * 128;
    const int n0  = (blk & 31) * 128;   // n%8 == blk%8 -> W slice pinned per XCD
    const size_t HSZ = 1024 * 1024;
    int ph = 0;

    float c0s[16], c1s[16];             // register-resident cell state
#pragma unroll
    for (int i = 0; i < 16; ++i) { c0s[i] = 0.f; c1s[i] = 0.f; }

    // ---- encoder
    gemm_full(Xbuf, 128, 128, 2, H0, 1024, Wc0, 1152, B0p, c0s, H0 + HSZ, m0, n0, smem);
    grid_bar(bar, ++ph);
    for (int s = 0; s < 48; ++s) {
        const u16* h0w = H0 + (size_t)((s + 1) & 1) * HSZ;
        gemm_full(h0w, 1024, 1024, 17, H1 + (size_t)(s & 1) * HSZ, 1024,
                  Wc1, 2048, B1p, c1s, H1 + (size_t)((s + 1) & 1) * HSZ, m0, n0, smem);
        gemm_full(Xbuf + (size_t)(s + 1) * (1024 * 128), 128, 128, 2, h0w, 1024,
                  Wc0, 1152, B0p, c0s, H0 + (size_t)(s & 1) * HSZ, m0, n0, smem);
        grid_bar(bar, ++ph);
    }
    gemm_full(H0 + HSZ, 1024, 1024, 17, H1, 1024,
              Wc1, 2048, B1p, c1s, H1 + HSZ, m0, n0, smem);   // step 48
    grid_bar(bar, ++ph);

    // ---- decoder
    // G0(49): DEC[0] + h0(48)=H0[1] -> H0[0]
    gemm_full(DEC, 128, 128, 17, H0 + HSZ, 1024, Wc0, 1152, B0p, c0s, H0, m0, n0, smem);
    grid_bar(bar, ++ph);

    for (int s = 49; s < 99; ++s) {
        int d = s - 49;
        u16* h0w = H0 + (size_t)((s + 1) & 1) * HSZ;   // h0(s)
        u16* h1r = H1 + (size_t)(s & 1) * HSZ;
        u16* h1w = H1 + (size_t)((s + 1) & 1) * HSZ;

        // phase A: G1(s)
        gemm_full(h0w, 1024, 1024, 17, h1r, 1024, Wc1, 2048, B1p, c1s, h1w, m0, n0, smem);
        grid_bar(bar, ++ph);

        // phase B: fc(s) (all blocks, quad-redundant) + G0(s+1) h0-part
        const float* decprev = (d == 0) ? (x + 49 * 66) : (out + (size_t)(d - 1) * 66);
        fc_share(blk, h1w, fcwb, fcb, alpha, beta, decprev, out + (size_t)d * 66,
                 DEC + (size_t)((d + 1) & 1) * (1024 * 128), smem);

        v4f acc[4][4];
        if (s < 98) {
#pragma unroll
            for (int i = 0; i < 4; ++i)
#pragma unroll
                for (int j = 0; j < 4; ++j) acc[i][j] = (v4f){0.f, 0.f, 0.f, 0.f};
            // tiles 2..18 : the h0-part (k0 >= 128), A2 = h0(s)
            gemm_tiles(acc, DEC, 128, 128, 17, h0w, 1024, Wc0, 1152,
                       m0, n0, smem, 2, 18);
        }
        grid_bar(bar, ++ph);

        // phase C: G0(s+1) DEC-part (tiles 0..2) + epilogue -> h0(s+1)
        if (s < 98) {
            const u16* A1 = DEC + (size_t)((d + 1) & 1) * (1024 * 128);
            gemm_tiles(acc, A1, 128, 128, 17, h0w, 1024, Wc0, 1152,
                       m0, n0, smem, 0, 2);
            gemm_epilogue(acc, B0p, c0s, H0 + (size_t)(s & 1) * HSZ, m0, n0, smem);
            grid_bar(bar, ++ph);
        }
    }
}

// ---------------------------------------------------------------------------
// init kernels
// ---------------------------------------------------------------------------
__global__ void k_init_w0(const float* __restrict__ Wih, const float* __restrict__ Whh,
                          u16* __restrict__ Wc)
{
    int idx = blockIdx.x * 256 + threadIdx.x;
    if (idx >= 4096 * 1152) return;
    int jp = idx / 1152, k = idx - jp * 1152;
    int u = jp >> 2, g = jp & 3;           // j' = u*4+g
    float v = 0.f;
    if (k < 66)        v = Wih[(g * 1024 + u) * 66 + k];
    else if (k >= 128) v = Whh[(size_t)(g * 1024 + u) * 1024 + (k - 128)];
    Wc[idx] = f2bf(v);
}
__global__ void k_init_w1(const float* __restrict__ Wih, const float* __restrict__ Whh,
                          u16* __restrict__ Wc)
{
    int idx = blockIdx.x * 256 + threadIdx.x;   // 4096*2048
    int jp = idx >> 11, k = idx & 2047;
    int u = jp >> 2, g = jp & 3;
    float v = (k < 1024) ? Wih[(size_t)(g * 1024 + u) * 1024 + k]
                         : Whh[(size_t)(g * 1024 + u) * 1024 + (k - 1024)];
    Wc[idx] = f2bf(v);
}
// fc weights -> fragment-contiguous: out[(((k>>5)*4+((k>>3)&3))*5+(r>>4))*128
//                                        + (r&15)*8 + (k&7)]
__global__ void k_init_fcw(const float* __restrict__ fcw, u16* __restrict__ Wb)
{
    int idx = blockIdx.x * 256 + threadIdx.x;   // 80*1024
    int r = idx >> 10, k = idx & 1023;
    float v = (r < 66) ? fcw[(size_t)r * 1024 + k] : 0.f;
    int o = (((k >> 5) * 4 + ((k >> 3) & 3)) * 5 + (r >> 4)) * 128
          + (r & 15) * 8 + (k & 7);
    Wb[o] = f2bf(v);
}
__global__ void k_init_bias(const float* __restrict__ b0, const float* __restrict__ b1,
                            float* __restrict__ B0p, float* __restrict__ B1p)
{
    int idx = blockIdx.x * 256 + threadIdx.x;   // 8192
    if (idx < 4096) B0p[idx] = b0[(idx & 3) * 1024 + (idx >> 2)];
    else { int j = idx - 4096; B1p[j] = b1[(j & 3) * 1024 + (j >> 2)]; }
}
__global__ void k_init_x(const float* __restrict__ x, u16* __restrict__ Xbuf,
                         u16* __restrict__ DEC0)
{
    int idx = blockIdx.x * 256 + threadIdx.x;   // 50*1024*128
    int t = idx >> 17;
    int b = (idx >> 7) & 1023;
    int c = idx & 127;
    float v = (c < 66) ? x[(size_t)b * 3300 + t * 66 + c] : 0.f;
    u16 h = f2bf(v);
    if (t < 49) Xbuf[idx] = h;
    else        DEC0[b * 128 + c] = h;
}
__global__ void k_init_state(u16* __restrict__ H0z, u16* __restrict__ H1z,
                             u16* __restrict__ DEC1, unsigned* __restrict__ bar)
{
    int idx = blockIdx.x * 256 + threadIdx.x;   // 1024*1024
    H0z[idx] = 0; H1z[idx] = 0;
    if (idx < 1024 * 128) DEC1[idx] = 0;
    if (idx < 1024) bar[idx] = 0u;
}

// ---------------------------------------------------------------------------
extern "C" void kernel_launch(void* const* d_in, const int* in_sizes, int n_in,
                              void* d_out, int out_size, void* d_ws, size_t ws_size,
                              hipStream_t stream)
{
    const float* x     = (const float*)d_in[0];
    const float* Wih0  = (const float*)d_in[1];
    const float* Whh0  = (const float*)d_in[2];
    const float* b0    = (const float*)d_in[3];
    const float* Wih1  = (const float*)d_in[4];
    const float* Whh1  = (const float*)d_in[5];
    const float* b1    = (const float*)d_in[6];
    const float* fcw   = (const float*)d_in[7];
    const float* fcb   = (const float*)d_in[8];
    const float* alpha = (const float*)d_in[9];
    const float* beta  = (const float*)d_in[10];
    float* out = (float*)d_out;

    char* p = (char*)d_ws;
    auto take = [&](size_t bytes) { char* r = p; p += (bytes + 255) & ~(size_t)255; return r; };
    u16*      Wc0  = (u16*)take((size_t)4096 * 1152 * 2);
    u16*      Wc1  = (u16*)take((size_t)4096 * 2048 * 2);
    u16*      fcwb = (u16*)take((size_t)80 * 1024 * 2);
    float*    B0p  = (float*)take(4096 * 4);
    float*    B1p  = (float*)take(4096 * 4);
    u16*      Xbuf = (u16*)take((size_t)49 * 1024 * 128 * 2);
    u16*      DEC  = (u16*)take((size_t)2 * 1024 * 128 * 2);
    u16*      H0   = (u16*)take((size_t)2 * 1024 * 1024 * 2);
    u16*      H1   = (u16*)take((size_t)2 * 1024 * 1024 * 2);
    unsigned* bar  = (unsigned*)take(4096);

    k_init_w0<<<18432, 256, 0, stream>>>(Wih0, Whh0, Wc0);
    k_init_w1<<<32768, 256, 0, stream>>>(Wih1, Whh1, Wc1);
    k_init_fcw<<<320, 256, 0, stream>>>(fcw, fcwb);
    k_init_bias<<<32, 256, 0, stream>>>(b0, b1, B0p, B1p);
    k_init_x<<<25600, 256, 0, stream>>>(x, Xbuf, DEC);
    k_init_state<<<4096, 256, 0, stream>>>(H0, H1, DEC + 1024 * 128, bar);

    lstm_persistent<<<dim3(256), 256, 0, stream>>>(
        Xbuf, DEC, H0, H1, Wc0, Wc1, B0p, B1p,
        fcwb, fcb, alpha, beta, x, out, bar);
}